// Round 1
// baseline (803.352 us; speedup 1.0000x reference)
//
#include <hip/hip_runtime.h>

#define BB 2
#define SS 2048
#define DD 512
#define HH 8
#define DKK 64
#define NROWS (BB * SS)          // 4096
#define Y_SIZE (BB * SS * DD)    // 2097152
#define BHN (BB * HH)            // 16

// ---------------- 64x64 tile GEMM core, BK=16, 256 threads, 4x4 microtile ----

__device__ __forceinline__ void mac16(float (&acc)[4][4],
                                      const float (*As)[64], const float (*Bs)[64],
                                      int tx, int ty) {
#pragma unroll
  for (int kk = 0; kk < 16; ++kk) {
    float4 a = *(const float4*)&As[kk][ty * 4];
    float4 b = *(const float4*)&Bs[kk][tx * 4];
    float av[4] = {a.x, a.y, a.z, a.w};
    float bv[4] = {b.x, b.y, b.z, b.w};
#pragma unroll
    for (int i = 0; i < 4; ++i)
#pragma unroll
      for (int j = 0; j < 4; ++j) acc[i][j] = fmaf(av[i], bv[j], acc[i][j]);
  }
}

// A: [64 rows m][K], row-major (k contiguous). B: [K][ldb], n contiguous.
__device__ __forceinline__ void gemm_nn(const float* __restrict__ A, int lda,
                                        const float* __restrict__ B, int ldb, int K,
                                        float (&acc)[4][4], float (*As)[64], float (*Bs)[64]) {
  const int t = threadIdx.x;
  const int tx = t & 15, ty = t >> 4;
  const int ar = t >> 2, ac = (t & 3) * 4;
  const int br = t >> 4, bc = (t & 15) * 4;
  for (int k0 = 0; k0 < K; k0 += 16) {
    float4 av = *(const float4*)&A[(size_t)ar * lda + k0 + ac];
    float4 bv = *(const float4*)&B[(size_t)(k0 + br) * ldb + bc];
    __syncthreads();
    As[ac + 0][ar] = av.x; As[ac + 1][ar] = av.y;
    As[ac + 2][ar] = av.z; As[ac + 3][ar] = av.w;
    *(float4*)&Bs[br][bc] = bv;
    __syncthreads();
    mac16(acc, As, Bs, tx, ty);
  }
}

// A: [64 rows m][K] row-major; B: [64 rows n][K] row-major (both k contiguous).
__device__ __forceinline__ void gemm_nt(const float* __restrict__ A, int lda,
                                        const float* __restrict__ B, int ldb, int K,
                                        float (&acc)[4][4], float (*As)[64], float (*Bs)[64]) {
  const int t = threadIdx.x;
  const int tx = t & 15, ty = t >> 4;
  const int r = t >> 2, c = (t & 3) * 4;
  for (int k0 = 0; k0 < K; k0 += 16) {
    float4 av = *(const float4*)&A[(size_t)r * lda + k0 + c];
    float4 bv = *(const float4*)&B[(size_t)r * ldb + k0 + c];
    __syncthreads();
    As[c + 0][r] = av.x; As[c + 1][r] = av.y; As[c + 2][r] = av.z; As[c + 3][r] = av.w;
    Bs[c + 0][r] = bv.x; Bs[c + 1][r] = bv.y; Bs[c + 2][r] = bv.z; Bs[c + 3][r] = bv.w;
    __syncthreads();
    mac16(acc, As, Bs, tx, ty);
  }
}

// ---------------- kernels ----------------

__global__ __launch_bounds__(256) void proj_qkv_kernel(
    const float* __restrict__ x,
    const float* __restrict__ wq, const float* __restrict__ bq,
    const float* __restrict__ wk, const float* __restrict__ bk,
    const float* __restrict__ wv, const float* __restrict__ bv,
    float* __restrict__ qo, float* __restrict__ ko, float* __restrict__ vo) {
  __shared__ float As[16][64], Bs[16][64];
  const float* W; const float* bias; float* out;
  if (blockIdx.z == 0) { W = wq; bias = bq; out = qo; }
  else if (blockIdx.z == 1) { W = wk; bias = bk; out = ko; }
  else { W = wv; bias = bv; out = vo; }
  const int m0 = blockIdx.x * 64;
  const int h = blockIdx.y;       // each 64-wide n-tile is exactly one head
  const int n0 = h * 64;
  float acc[4][4] = {};
  gemm_nn(x + (size_t)m0 * DD, DD, W + n0, DD, DD, acc, As, Bs);
  const int tx = threadIdx.x & 15, ty = threadIdx.x >> 4;
  float4 bb = *(const float4*)&bias[n0 + tx * 4];
#pragma unroll
  for (int i = 0; i < 4; ++i) {
    int m = m0 + ty * 4 + i;
    int b = m >> 11, s = m & (SS - 1);
    float4 o;
    o.x = acc[i][0] + bb.x; o.y = acc[i][1] + bb.y;
    o.z = acc[i][2] + bb.z; o.w = acc[i][3] + bb.w;
    *(float4*)&out[((size_t)(b * HH + h) * SS + s) * DKK + tx * 4] = o;
  }
}

__global__ __launch_bounds__(256) void gate_kernel(
    const float* __restrict__ x, const float* __restrict__ g1w,
    const float* __restrict__ g1b, const float* __restrict__ g2w,
    const float* __restrict__ g2b, float* __restrict__ gate) {
  __shared__ float xs[8][512];
  __shared__ float red[32];
  const int r0 = blockIdx.x * 8;
  const int t = threadIdx.x;
  const float4* xg = (const float4*)&x[(size_t)r0 * DD];
  float4* xsv = (float4*)&xs[0][0];
#pragma unroll
  for (int i = 0; i < 4; ++i) xsv[t + i * 256] = xg[t + i * 256];
  __syncthreads();
  float acc[8] = {};
  for (int i = 0; i < 512; i += 4) {
    float w0 = g1w[(i + 0) * 256 + t];
    float w1 = g1w[(i + 1) * 256 + t];
    float w2 = g1w[(i + 2) * 256 + t];
    float w3 = g1w[(i + 3) * 256 + t];
#pragma unroll
    for (int r = 0; r < 8; ++r) {
      float4 xv = *(const float4*)&xs[r][i];
      acc[r] += xv.x * w0 + xv.y * w1 + xv.z * w2 + xv.w * w3;
    }
  }
  float b1 = g1b[t], w2_ = g2w[t];
  float p[8];
#pragma unroll
  for (int r = 0; r < 8; ++r) {
    float h = acc[r] + b1;
    h = h > 0.f ? h : 0.f;
    p[r] = h * w2_;
  }
#pragma unroll
  for (int r = 0; r < 8; ++r)
    for (int off = 32; off; off >>= 1) p[r] += __shfl_xor(p[r], off, 64);
  if ((t & 63) == 0) {
#pragma unroll
    for (int r = 0; r < 8; ++r) red[r * 4 + (t >> 6)] = p[r];
  }
  __syncthreads();
  if (t < 8) {
    float s = red[t * 4] + red[t * 4 + 1] + red[t * 4 + 2] + red[t * 4 + 3] + g2b[0];
    gate[r0 + t] = 1.f / (1.f + __expf(-s));
  }
}

__global__ __launch_bounds__(256) void scores_kernel(
    const float* __restrict__ q, const float* __restrict__ kmat,
    float* __restrict__ attn) {
  __shared__ float As[16][64], Bs[16][64];
  const int z = blockIdx.z;        // b*H + h
  const int m0 = blockIdx.x * 64;  // query tile
  const int n0 = blockIdx.y * 64;  // key tile
  const float* A = q + (size_t)z * SS * DKK + (size_t)m0 * DKK;
  const float* B = kmat + (size_t)z * SS * DKK + (size_t)n0 * DKK;
  float acc[4][4] = {};
  gemm_nt(A, DKK, B, DKK, DKK, acc, As, Bs);
  const int tx = threadIdx.x & 15, ty = threadIdx.x >> 4;
  float* out = attn + (size_t)z * SS * SS;
#pragma unroll
  for (int i = 0; i < 4; ++i) {
    int qi = m0 + ty * 4 + i;
    float4 o;
#pragma unroll
    for (int j = 0; j < 4; ++j) {
      int kj = n0 + tx * 4 + j;
      float bias = (kj <= qi) ? __expf(-0.02f * (float)(qi - kj)) : 0.f;
      ((float*)&o)[j] = acc[i][j] * 0.125f + bias;
    }
    *(float4*)&out[(size_t)qi * SS + n0 + tx * 4] = o;
  }
}

__global__ __launch_bounds__(256) void softmax_kernel(float* __restrict__ attn) {
  __shared__ float sred[8];
  const int qi = blockIdx.x, z = blockIdx.y;
  float* row = attn + ((size_t)z * SS + qi) * SS;
  const int t = threadIdx.x;
  float4 v0 = *(float4*)&row[t * 8];
  float4 v1 = *(float4*)&row[t * 8 + 4];
  float m = fmaxf(fmaxf(fmaxf(v0.x, v0.y), fmaxf(v0.z, v0.w)),
                  fmaxf(fmaxf(v1.x, v1.y), fmaxf(v1.z, v1.w)));
  for (int off = 32; off; off >>= 1) m = fmaxf(m, __shfl_xor(m, off, 64));
  if ((t & 63) == 0) sred[t >> 6] = m;
  __syncthreads();
  m = fmaxf(fmaxf(sred[0], sred[1]), fmaxf(sred[2], sred[3]));
  float e[8];
  e[0] = __expf(v0.x - m); e[1] = __expf(v0.y - m);
  e[2] = __expf(v0.z - m); e[3] = __expf(v0.w - m);
  e[4] = __expf(v1.x - m); e[5] = __expf(v1.y - m);
  e[6] = __expf(v1.z - m); e[7] = __expf(v1.w - m);
  float s = ((e[0] + e[1]) + (e[2] + e[3])) + ((e[4] + e[5]) + (e[6] + e[7]));
  for (int off = 32; off; off >>= 1) s += __shfl_xor(s, off, 64);
  if ((t & 63) == 0) sred[4 + (t >> 6)] = s;
  __syncthreads();
  s = sred[4] + sred[5] + sred[6] + sred[7];
  float inv = 1.f / s;
  v0.x = e[0] * inv; v0.y = e[1] * inv; v0.z = e[2] * inv; v0.w = e[3] * inv;
  v1.x = e[4] * inv; v1.y = e[5] * inv; v1.z = e[6] * inv; v1.w = e[7] * inv;
  *(float4*)&row[t * 8] = v0;
  *(float4*)&row[t * 8 + 4] = v1;
}

__global__ __launch_bounds__(256) void av_kernel(
    const float* __restrict__ attn, const float* __restrict__ v,
    float* __restrict__ ctx) {
  __shared__ float As[16][64], Bs[16][64];
  const int z = blockIdx.y;        // b*H + h
  const int m0 = blockIdx.x * 64;  // query tile
  const float* A = attn + (size_t)z * SS * SS + (size_t)m0 * SS;
  const float* B = v + (size_t)z * SS * DKK;
  float acc[4][4] = {};
  gemm_nn(A, SS, B, DKK, SS, acc, As, Bs);
  const int tx = threadIdx.x & 15, ty = threadIdx.x >> 4;
  const int b = z >> 3, h = z & 7;
#pragma unroll
  for (int i = 0; i < 4; ++i) {
    int s = m0 + ty * 4 + i;
    float4 o = {acc[i][0], acc[i][1], acc[i][2], acc[i][3]};
    *(float4*)&ctx[(size_t)(b * SS + s) * DD + h * DKK + tx * 4] = o;
  }
}

__global__ __launch_bounds__(256) void proj_o_kernel(
    const float* __restrict__ ctx, const float* __restrict__ wo,
    const float* __restrict__ bo, float* __restrict__ o) {
  __shared__ float As[16][64], Bs[16][64];
  const int m0 = blockIdx.x * 64, n0 = blockIdx.y * 64;
  float acc[4][4] = {};
  gemm_nn(ctx + (size_t)m0 * DD, DD, wo + n0, DD, DD, acc, As, Bs);
  const int tx = threadIdx.x & 15, ty = threadIdx.x >> 4;
  float4 bb = *(const float4*)&bo[n0 + tx * 4];
#pragma unroll
  for (int i = 0; i < 4; ++i) {
    int m = m0 + ty * 4 + i;
    float4 ov;
    ov.x = acc[i][0] + bb.x; ov.y = acc[i][1] + bb.y;
    ov.z = acc[i][2] + bb.z; ov.w = acc[i][3] + bb.w;
    *(float4*)&o[(size_t)m * DD + n0 + tx * 4] = ov;
  }
}

__global__ __launch_bounds__(256) void blend_ln_kernel(
    const float* __restrict__ o, const float* __restrict__ x,
    const float* __restrict__ gate, const float* __restrict__ ln_g,
    const float* __restrict__ ln_b, float* __restrict__ y) {
  __shared__ float r1[4], r2[4];
  const int row = blockIdx.x, t = threadIdx.x;
  float g = gate[row];
  float2 o2 = *(const float2*)&o[(size_t)row * DD + t * 2];
  float2 x2 = *(const float2*)&x[(size_t)row * DD + t * 2];
  float va = o2.x * g + x2.x * (1.f - g);
  float vb = o2.y * g + x2.y * (1.f - g);
  float s = va + vb, q = va * va + vb * vb;
  for (int off = 32; off; off >>= 1) {
    s += __shfl_xor(s, off, 64);
    q += __shfl_xor(q, off, 64);
  }
  if ((t & 63) == 0) { r1[t >> 6] = s; r2[t >> 6] = q; }
  __syncthreads();
  s = r1[0] + r1[1] + r1[2] + r1[3];
  q = r2[0] + r2[1] + r2[2] + r2[3];
  float mean = s * (1.f / 512.f);
  float var = q * (1.f / 512.f) - mean * mean;
  float rstd = rsqrtf(var + 1e-5f);
  float2 lg = *(const float2*)&ln_g[t * 2];
  float2 lb = *(const float2*)&ln_b[t * 2];
  float2 out;
  out.x = (va - mean) * rstd * lg.x + lb.x;
  out.y = (vb - mean) * rstd * lg.y + lb.y;
  *(float2*)&y[(size_t)row * DD + t * 2] = out;
}

extern "C" void kernel_launch(void* const* d_in, const int* in_sizes, int n_in,
                              void* d_out, int out_size, void* d_ws, size_t ws_size,
                              hipStream_t stream) {
  const float* x   = (const float*)d_in[0];
  const float* wq  = (const float*)d_in[1];
  const float* bq  = (const float*)d_in[2];
  const float* wk  = (const float*)d_in[3];
  const float* bk  = (const float*)d_in[4];
  const float* wv  = (const float*)d_in[5];
  const float* bv  = (const float*)d_in[6];
  const float* wo  = (const float*)d_in[7];
  const float* bo  = (const float*)d_in[8];
  const float* g1w = (const float*)d_in[9];
  const float* g1b = (const float*)d_in[10];
  const float* g2w = (const float*)d_in[11];
  const float* g2b = (const float*)d_in[12];
  const float* lng = (const float*)d_in[13];
  const float* lnb = (const float*)d_in[14];

  float* y    = (float*)d_out;
  float* attn = y + (size_t)Y_SIZE;

  float* ws   = (float*)d_ws;
  float* q    = ws;
  float* k    = q + (size_t)NROWS * DD;
  float* v    = k + (size_t)NROWS * DD;
  float* ctx  = v + (size_t)NROWS * DD;
  float* o    = ctx + (size_t)NROWS * DD;
  float* gate = o + (size_t)NROWS * DD;

  hipLaunchKernelGGL(proj_qkv_kernel, dim3(64, 8, 3), dim3(256), 0, stream,
                     x, wq, bq, wk, bk, wv, bv, q, k, v);
  hipLaunchKernelGGL(gate_kernel, dim3(512), dim3(256), 0, stream,
                     x, g1w, g1b, g2w, g2b, gate);
  hipLaunchKernelGGL(scores_kernel, dim3(32, 32, 16), dim3(256), 0, stream,
                     q, k, attn);
  hipLaunchKernelGGL(softmax_kernel, dim3(2048, 16), dim3(256), 0, stream, attn);
  hipLaunchKernelGGL(av_kernel, dim3(32, 16), dim3(256), 0, stream, attn, v, ctx);
  hipLaunchKernelGGL(proj_o_kernel, dim3(64, 8), dim3(256), 0, stream,
                     ctx, wo, bo, o);
  hipLaunchKernelGGL(blend_ln_kernel, dim3(4096), dim3(256), 0, stream,
                     o, x, gate, lng, lnb, y);
}

// Round 2
// 442.362 us; speedup vs baseline: 1.8161x; 1.8161x over previous
//
#include <hip/hip_runtime.h>

#define BB 2
#define SS 2048
#define DD 512
#define HH 8
#define DKK 64
#define NROWS (BB * SS)          // 4096
#define Y_SIZE (BB * SS * DD)    // 2097152

typedef __attribute__((ext_vector_type(8))) short short8;
typedef __attribute__((ext_vector_type(4))) float f32x4;

__device__ __forceinline__ ushort f2bf(float f) {
  union { float f; unsigned u; } v; v.f = f;
  unsigned u = v.u;
  return (ushort)((u + 0x7fffu + ((u >> 16) & 1u)) >> 16);
}

// ---------------- converts ----------------

__global__ __launch_bounds__(256) void conv_x_kernel(const float* __restrict__ x,
                                                     ushort* __restrict__ xb) {
  int i = (blockIdx.x * 256 + threadIdx.x) * 4;
  float4 v = *(const float4*)(x + i);
  ushort4 o = {f2bf(v.x), f2bf(v.y), f2bf(v.z), f2bf(v.w)};
  *(ushort4*)(xb + i) = o;
}

// transpose 512x512 fp32 w[k][n] -> bf16 wt[n][k]
__global__ __launch_bounds__(256) void conv_wt_kernel(
    const float* __restrict__ w0, const float* __restrict__ w1,
    const float* __restrict__ w2, const float* __restrict__ w3,
    ushort* __restrict__ o0, ushort* __restrict__ o1,
    ushort* __restrict__ o2, ushort* __restrict__ o3) {
  __shared__ float T[64][65];
  const float* w; ushort* wt;
  switch (blockIdx.z) {
    case 0: w = w0; wt = o0; break;
    case 1: w = w1; wt = o1; break;
    case 2: w = w2; wt = o2; break;
    default: w = w3; wt = o3; break;
  }
  const int t = threadIdx.x;
  const int n0 = blockIdx.x * 64, k0 = blockIdx.y * 64;
#pragma unroll
  for (int i = 0; i < 4; ++i) {
    int c = t + i * 256;
    int row = c >> 4, cc = c & 15;
    float4 v = *(const float4*)(w + (size_t)(k0 + row) * DD + n0 + cc * 4);
    T[row][cc * 4 + 0] = v.x; T[row][cc * 4 + 1] = v.y;
    T[row][cc * 4 + 2] = v.z; T[row][cc * 4 + 3] = v.w;
  }
  __syncthreads();
#pragma unroll
  for (int i = 0; i < 2; ++i) {
    int c = t + i * 256;
    int nr = c >> 3, kc = c & 7;
    ushort4 a, b;
    a.x = f2bf(T[kc * 8 + 0][nr]); a.y = f2bf(T[kc * 8 + 1][nr]);
    a.z = f2bf(T[kc * 8 + 2][nr]); a.w = f2bf(T[kc * 8 + 3][nr]);
    b.x = f2bf(T[kc * 8 + 4][nr]); b.y = f2bf(T[kc * 8 + 5][nr]);
    b.z = f2bf(T[kc * 8 + 6][nr]); b.w = f2bf(T[kc * 8 + 7][nr]);
    *(ushort4*)(wt + (size_t)(n0 + nr) * DD + k0 + kc * 8) = a;
    *(ushort4*)(wt + (size_t)(n0 + nr) * DD + k0 + kc * 8 + 4) = b;
  }
}

// ---------------- shared MFMA GEMM body: 64x64 tile, BK=64, NT form ----------
// A rows [m][k] k-contig, B rows [n][k] k-contig, both bf16(ushort).

__device__ __forceinline__ void mfma_gemm64(
    const ushort* __restrict__ A, int lda, const ushort* __restrict__ B, int ldb,
    int K, ushort (*As)[72], ushort (*Bs)[72], f32x4 (&acc)[2][2], int t) {
  const int l = t & 63, w = t >> 6;
  const int mq = w & 1, nq = w >> 1;
  const int l15 = l & 15, l4 = l >> 4;
  for (int k0 = 0; k0 < K; k0 += 64) {
    __syncthreads();
#pragma unroll
    for (int i = 0; i < 2; ++i) {
      int c = t + i * 256;
      int row = c >> 3, cc = c & 7;
      *(uint4*)&As[row][cc * 8] = *(const uint4*)(A + (size_t)row * lda + k0 + cc * 8);
      *(uint4*)&Bs[row][cc * 8] = *(const uint4*)(B + (size_t)row * ldb + k0 + cc * 8);
    }
    __syncthreads();
    short8 af[2][2], bf[2][2];
#pragma unroll
    for (int mt = 0; mt < 2; ++mt)
#pragma unroll
      for (int ks = 0; ks < 2; ++ks)
        af[mt][ks] = *(const short8*)&As[32 * mq + 16 * mt + l15][ks * 32 + l4 * 8];
#pragma unroll
    for (int nt = 0; nt < 2; ++nt)
#pragma unroll
      for (int ks = 0; ks < 2; ++ks)
        bf[nt][ks] = *(const short8*)&Bs[32 * nq + 16 * nt + l15][ks * 32 + l4 * 8];
#pragma unroll
    for (int mt = 0; mt < 2; ++mt)
#pragma unroll
      for (int nt = 0; nt < 2; ++nt)
#pragma unroll
        for (int ks = 0; ks < 2; ++ks)
          acc[mt][nt] = __builtin_amdgcn_mfma_f32_16x16x32_bf16(
              af[mt][ks], bf[nt][ks], acc[mt][nt], 0, 0, 0);
  }
}

// ---------------- QKV projection ----------------
// out: q,k as bf16 [z][s][dk]; v transposed bf16 [z][dk][s]

__global__ __launch_bounds__(256) void proj_qkv_kernel(
    const ushort* __restrict__ xb,
    const ushort* __restrict__ wqt, const float* __restrict__ bq,
    const ushort* __restrict__ wkt, const float* __restrict__ bk,
    const ushort* __restrict__ wvt, const float* __restrict__ bv,
    ushort* __restrict__ qb, ushort* __restrict__ kb, ushort* __restrict__ vt) {
  __shared__ ushort As[64][72], Bs[64][72];
  const ushort* W; const float* bias; ushort* out;
  if (blockIdx.z == 0) { W = wqt; bias = bq; out = qb; }
  else if (blockIdx.z == 1) { W = wkt; bias = bk; out = kb; }
  else { W = wvt; bias = bv; out = vt; }
  const int m0 = blockIdx.x * 64;
  const int h = blockIdx.y;
  const int t = threadIdx.x;
  const int l = t & 63, w = t >> 6;
  const int mq = w & 1, nq = w >> 1;
  const int l15 = l & 15, l4 = l >> 4;
  f32x4 acc[2][2] = {};
  mfma_gemm64(xb + (size_t)m0 * DD, DD, W + (size_t)h * DKK * DD, DD, DD,
              As, Bs, acc, t);
  float biasv[2];
#pragma unroll
  for (int nt = 0; nt < 2; ++nt) biasv[nt] = bias[h * DKK + 32 * nq + 16 * nt + l15];

  if (blockIdx.z < 2) {
    // bounce via LDS, store [z][s][dk] coalesced
    __syncthreads();
#pragma unroll
    for (int mt = 0; mt < 2; ++mt)
#pragma unroll
      for (int nt = 0; nt < 2; ++nt)
#pragma unroll
        for (int r = 0; r < 4; ++r)
          As[32 * mq + 16 * mt + l4 * 4 + r][32 * nq + 16 * nt + l15] =
              f2bf(acc[mt][nt][r] + biasv[nt]);
    __syncthreads();
#pragma unroll
    for (int i = 0; i < 2; ++i) {
      int c = t + i * 256;
      int row = c >> 3, cc = c & 7;
      int m = m0 + row, b = m >> 11, s = m & (SS - 1);
      uint4 v = *(const uint4*)&As[row][cc * 8];
      *(uint4*)(out + ((size_t)(b * HH + h) * SS + s) * DKK + cc * 8) = v;
    }
  } else {
    // v: direct transposed store [z][dk][s]
#pragma unroll
    for (int mt = 0; mt < 2; ++mt)
#pragma unroll
      for (int nt = 0; nt < 2; ++nt) {
        int dk = 32 * nq + 16 * nt + l15;
        int m = m0 + 32 * mq + 16 * mt + l4 * 4;
        int b = m >> 11, sb = m & (SS - 1);
        ushort4 pk;
        pk.x = f2bf(acc[mt][nt][0] + biasv[nt]);
        pk.y = f2bf(acc[mt][nt][1] + biasv[nt]);
        pk.z = f2bf(acc[mt][nt][2] + biasv[nt]);
        pk.w = f2bf(acc[mt][nt][3] + biasv[nt]);
        *(ushort4*)(out + ((size_t)(b * HH + h) * DKK + dk) * SS + sb) = pk;
      }
  }
}

// ---------------- fused attention: scores + softmax + AV ----------------
// grid (32 qtiles, 16 z). Recompute QK^T twice; no max-shift needed
// (|score| <= ~4, bias <= 1 -> exp safe in fp32).

__global__ __launch_bounds__(256) void attn_kernel(
    const ushort* __restrict__ qb, const ushort* __restrict__ kb,
    const ushort* __restrict__ vt, float* __restrict__ attn,
    ushort* __restrict__ ctx) {
  __shared__ ushort Ks[64][72], Vs[64][72], Ps[64][72];
  __shared__ float rs[64];
  const int t = threadIdx.x;
  const int l = t & 63, w = t >> 6;
  const int mq = w & 1, nq = w >> 1;
  const int l15 = l & 15, l4 = l >> 4;
  const int z = blockIdx.y;
  const int q0 = blockIdx.x * 64;
  if (t < 64) rs[t] = 0.f;

  // Q fragments in registers for the whole kernel
  short8 qf[2][2];
#pragma unroll
  for (int mt = 0; mt < 2; ++mt)
#pragma unroll
    for (int ks = 0; ks < 2; ++ks)
      qf[mt][ks] = *(const short8*)(qb +
          ((size_t)z * SS + q0 + 32 * mq + 16 * mt + l15) * DKK + ks * 32 + l4 * 8);

  float rowf[2][4]; int qi_[2][4];
#pragma unroll
  for (int mt = 0; mt < 2; ++mt)
#pragma unroll
    for (int r = 0; r < 4; ++r) {
      int qi = q0 + 32 * mq + 16 * mt + l4 * 4 + r;
      qi_[mt][r] = qi;
      rowf[mt][r] = __expf(-0.02f * (float)qi);
    }

  float rsp[2][4] = {};
  // ---- pass 1: row sums of exp(score) ----
  for (int kt = 0; kt < 32; ++kt) {
    __syncthreads();
#pragma unroll
    for (int i = 0; i < 2; ++i) {
      int c = t + i * 256;
      int row = c >> 3, cc = c & 7;
      *(uint4*)&Ks[row][cc * 8] =
          *(const uint4*)(kb + ((size_t)z * SS + kt * 64 + row) * DKK + cc * 8);
    }
    __syncthreads();
    short8 bf[2][2];
#pragma unroll
    for (int nt = 0; nt < 2; ++nt)
#pragma unroll
      for (int ks = 0; ks < 2; ++ks)
        bf[nt][ks] = *(const short8*)&Ks[32 * nq + 16 * nt + l15][ks * 32 + l4 * 8];
    f32x4 acc[2][2] = {};
#pragma unroll
    for (int mt = 0; mt < 2; ++mt)
#pragma unroll
      for (int nt = 0; nt < 2; ++nt)
#pragma unroll
        for (int ks = 0; ks < 2; ++ks)
          acc[mt][nt] = __builtin_amdgcn_mfma_f32_16x16x32_bf16(
              qf[mt][ks], bf[nt][ks], acc[mt][nt], 0, 0, 0);
#pragma unroll
    for (int nt = 0; nt < 2; ++nt) {
      int kj = kt * 64 + 32 * nq + 16 * nt + l15;
      float colf = __expf(0.02f * (float)kj);
#pragma unroll
      for (int mt = 0; mt < 2; ++mt)
#pragma unroll
        for (int r = 0; r < 4; ++r) {
          float bias = (kj <= qi_[mt][r]) ? rowf[mt][r] * colf : 0.f;
          rsp[mt][r] += __expf(fmaf(acc[mt][nt][r], 0.125f, bias));
        }
    }
  }
  // reduce row sums: shuffle over the 16 lanes sharing a row, then LDS
#pragma unroll
  for (int mt = 0; mt < 2; ++mt)
#pragma unroll
    for (int r = 0; r < 4; ++r) {
      float v = rsp[mt][r];
      v += __shfl_xor(v, 1); v += __shfl_xor(v, 2);
      v += __shfl_xor(v, 4); v += __shfl_xor(v, 8);
      if (l15 == 0) atomicAdd(&rs[32 * mq + 16 * mt + l4 * 4 + r], v);
    }
  __syncthreads();
  float inv[2][4];
#pragma unroll
  for (int mt = 0; mt < 2; ++mt)
#pragma unroll
    for (int r = 0; r < 4; ++r)
      inv[mt][r] = 1.f / rs[32 * mq + 16 * mt + l4 * 4 + r];

  // ---- pass 2: recompute, normalize, write attn, accumulate PV ----
  f32x4 oacc[2][2] = {};
  for (int kt = 0; kt < 32; ++kt) {
    __syncthreads();
#pragma unroll
    for (int i = 0; i < 2; ++i) {
      int c = t + i * 256;
      int row = c >> 3, cc = c & 7;
      *(uint4*)&Ks[row][cc * 8] =
          *(const uint4*)(kb + ((size_t)z * SS + kt * 64 + row) * DKK + cc * 8);
      *(uint4*)&Vs[row][cc * 8] =
          *(const uint4*)(vt + ((size_t)z * DKK + row) * SS + kt * 64 + cc * 8);
    }
    __syncthreads();
    short8 bf[2][2];
#pragma unroll
    for (int nt = 0; nt < 2; ++nt)
#pragma unroll
      for (int ks = 0; ks < 2; ++ks)
        bf[nt][ks] = *(const short8*)&Ks[32 * nq + 16 * nt + l15][ks * 32 + l4 * 8];
    f32x4 acc[2][2] = {};
#pragma unroll
    for (int mt = 0; mt < 2; ++mt)
#pragma unroll
      for (int nt = 0; nt < 2; ++nt)
#pragma unroll
        for (int ks = 0; ks < 2; ++ks)
          acc[mt][nt] = __builtin_amdgcn_mfma_f32_16x16x32_bf16(
              qf[mt][ks], bf[nt][ks], acc[mt][nt], 0, 0, 0);
#pragma unroll
    for (int nt = 0; nt < 2; ++nt) {
      int kj = kt * 64 + 32 * nq + 16 * nt + l15;
      float colf = __expf(0.02f * (float)kj);
#pragma unroll
      for (int mt = 0; mt < 2; ++mt)
#pragma unroll
        for (int r = 0; r < 4; ++r) {
          float bias = (kj <= qi_[mt][r]) ? rowf[mt][r] * colf : 0.f;
          float p = __expf(fmaf(acc[mt][nt][r], 0.125f, bias)) * inv[mt][r];
          attn[((size_t)z * SS + qi_[mt][r]) * SS + kj] = p;
          Ps[32 * mq + 16 * mt + l4 * 4 + r][32 * nq + 16 * nt + l15] = f2bf(p);
        }
    }
    __syncthreads();
    short8 pa[2][2], pb[2][2];
#pragma unroll
    for (int mt = 0; mt < 2; ++mt)
#pragma unroll
      for (int ks = 0; ks < 2; ++ks)
        pa[mt][ks] = *(const short8*)&Ps[32 * mq + 16 * mt + l15][ks * 32 + l4 * 8];
#pragma unroll
    for (int nt = 0; nt < 2; ++nt)
#pragma unroll
      for (int ks = 0; ks < 2; ++ks)
        pb[nt][ks] = *(const short8*)&Vs[32 * nq + 16 * nt + l15][ks * 32 + l4 * 8];
#pragma unroll
    for (int mt = 0; mt < 2; ++mt)
#pragma unroll
      for (int nt = 0; nt < 2; ++nt)
#pragma unroll
        for (int ks = 0; ks < 2; ++ks)
          oacc[mt][nt] = __builtin_amdgcn_mfma_f32_16x16x32_bf16(
              pa[mt][ks], pb[nt][ks], oacc[mt][nt], 0, 0, 0);
  }
  // epilogue: ctx tile (bf16 [4096][512]) via LDS bounce
  __syncthreads();
#pragma unroll
  for (int mt = 0; mt < 2; ++mt)
#pragma unroll
    for (int nt = 0; nt < 2; ++nt)
#pragma unroll
      for (int r = 0; r < 4; ++r)
        Ps[32 * mq + 16 * mt + l4 * 4 + r][32 * nq + 16 * nt + l15] =
            f2bf(oacc[mt][nt][r]);
  __syncthreads();
  const int b = z >> 3, h = z & 7;
#pragma unroll
  for (int i = 0; i < 2; ++i) {
    int c = t + i * 256;
    int row = c >> 3, cc = c & 7;
    uint4 v = *(const uint4*)&Ps[row][cc * 8];
    *(uint4*)(ctx + ((size_t)(b * SS + q0 + row)) * DD + h * DKK + cc * 8) = v;
  }
}

// ---------------- O projection ----------------

__global__ __launch_bounds__(256) void proj_o_kernel(
    const ushort* __restrict__ ctx, const ushort* __restrict__ wot,
    const float* __restrict__ bo, float* __restrict__ o) {
  __shared__ ushort As[64][72], Bs[64][72];
  const int m0 = blockIdx.x * 64, n0 = blockIdx.y * 64;
  const int t = threadIdx.x;
  const int l = t & 63, w = t >> 6;
  const int mq = w & 1, nq = w >> 1;
  const int l15 = l & 15, l4 = l >> 4;
  f32x4 acc[2][2] = {};
  mfma_gemm64(ctx + (size_t)m0 * DD, DD, wot + (size_t)n0 * DD, DD, DD,
              As, Bs, acc, t);
#pragma unroll
  for (int nt = 0; nt < 2; ++nt) {
    int col = n0 + 32 * nq + 16 * nt + l15;
    float bv = bo[col];
#pragma unroll
    for (int mt = 0; mt < 2; ++mt)
#pragma unroll
      for (int r = 0; r < 4; ++r) {
        int m = m0 + 32 * mq + 16 * mt + l4 * 4 + r;
        o[(size_t)m * DD + col] = acc[mt][nt][r] + bv;
      }
  }
}

// ---------------- gate MLP (fp32, small) ----------------

__global__ __launch_bounds__(256) void gate_kernel(
    const float* __restrict__ x, const float* __restrict__ g1w,
    const float* __restrict__ g1b, const float* __restrict__ g2w,
    const float* __restrict__ g2b, float* __restrict__ gate) {
  __shared__ float xs[8][512];
  __shared__ float red[32];
  const int r0 = blockIdx.x * 8;
  const int t = threadIdx.x;
  const float4* xg = (const float4*)&x[(size_t)r0 * DD];
  float4* xsv = (float4*)&xs[0][0];
#pragma unroll
  for (int i = 0; i < 4; ++i) xsv[t + i * 256] = xg[t + i * 256];
  __syncthreads();
  float acc[8] = {};
  for (int i = 0; i < 512; i += 4) {
    float w0 = g1w[(i + 0) * 256 + t];
    float w1 = g1w[(i + 1) * 256 + t];
    float w2 = g1w[(i + 2) * 256 + t];
    float w3 = g1w[(i + 3) * 256 + t];
#pragma unroll
    for (int r = 0; r < 8; ++r) {
      float4 xv = *(const float4*)&xs[r][i];
      acc[r] += xv.x * w0 + xv.y * w1 + xv.z * w2 + xv.w * w3;
    }
  }
  float b1 = g1b[t], w2_ = g2w[t];
  float p[8];
#pragma unroll
  for (int r = 0; r < 8; ++r) {
    float h = acc[r] + b1;
    h = h > 0.f ? h : 0.f;
    p[r] = h * w2_;
  }
#pragma unroll
  for (int r = 0; r < 8; ++r)
    for (int off = 32; off; off >>= 1) p[r] += __shfl_xor(p[r], off, 64);
  if ((t & 63) == 0) {
#pragma unroll
    for (int r = 0; r < 8; ++r) red[r * 4 + (t >> 6)] = p[r];
  }
  __syncthreads();
  if (t < 8) {
    float s = red[t * 4] + red[t * 4 + 1] + red[t * 4 + 2] + red[t * 4 + 3] + g2b[0];
    gate[r0 + t] = 1.f / (1.f + __expf(-s));
  }
}

// ---------------- gated blend + layernorm ----------------

__global__ __launch_bounds__(256) void blend_ln_kernel(
    const float* __restrict__ o, const float* __restrict__ x,
    const float* __restrict__ gate, const float* __restrict__ ln_g,
    const float* __restrict__ ln_b, float* __restrict__ y) {
  __shared__ float r1[4], r2[4];
  const int row = blockIdx.x, t = threadIdx.x;
  float g = gate[row];
  float2 o2 = *(const float2*)&o[(size_t)row * DD + t * 2];
  float2 x2 = *(const float2*)&x[(size_t)row * DD + t * 2];
  float va = o2.x * g + x2.x * (1.f - g);
  float vb = o2.y * g + x2.y * (1.f - g);
  float s = va + vb, q = va * va + vb * vb;
  for (int off = 32; off; off >>= 1) {
    s += __shfl_xor(s, off, 64);
    q += __shfl_xor(q, off, 64);
  }
  if ((t & 63) == 0) { r1[t >> 6] = s; r2[t >> 6] = q; }
  __syncthreads();
  s = r1[0] + r1[1] + r1[2] + r1[3];
  q = r2[0] + r2[1] + r2[2] + r2[3];
  float mean = s * (1.f / 512.f);
  float var = q * (1.f / 512.f) - mean * mean;
  float rstd = rsqrtf(var + 1e-5f);
  float2 lg = *(const float2*)&ln_g[t * 2];
  float2 lb = *(const float2*)&ln_b[t * 2];
  float2 out;
  out.x = (va - mean) * rstd * lg.x + lb.x;
  out.y = (vb - mean) * rstd * lg.y + lb.y;
  *(float2*)&y[(size_t)row * DD + t * 2] = out;
}

extern "C" void kernel_launch(void* const* d_in, const int* in_sizes, int n_in,
                              void* d_out, int out_size, void* d_ws, size_t ws_size,
                              hipStream_t stream) {
  const float* x   = (const float*)d_in[0];
  const float* wq  = (const float*)d_in[1];
  const float* bq  = (const float*)d_in[2];
  const float* wk  = (const float*)d_in[3];
  const float* bk  = (const float*)d_in[4];
  const float* wv  = (const float*)d_in[5];
  const float* bv  = (const float*)d_in[6];
  const float* wo  = (const float*)d_in[7];
  const float* bo  = (const float*)d_in[8];
  const float* g1w = (const float*)d_in[9];
  const float* g1b = (const float*)d_in[10];
  const float* g2w = (const float*)d_in[11];
  const float* g2b = (const float*)d_in[12];
  const float* lng = (const float*)d_in[13];
  const float* lnb = (const float*)d_in[14];

  float* y    = (float*)d_out;
  float* attn = y + (size_t)Y_SIZE;

  char* ws = (char*)d_ws;
  ushort* xb  = (ushort*)(ws);                       // 4 MB
  ushort* wqt = (ushort*)(ws + (4 << 20));           // 512 KB
  ushort* wkt = (ushort*)(ws + (4 << 20) + (512 << 10));
  ushort* wvt = (ushort*)(ws + (5 << 20));
  ushort* wot = (ushort*)(ws + (5 << 20) + (512 << 10));
  ushort* qb  = (ushort*)(ws + (6 << 20));           // 4 MB
  ushort* kb  = (ushort*)(ws + (10 << 20));          // 4 MB
  ushort* vt  = (ushort*)(ws + (14 << 20));          // 4 MB
  ushort* ctx = (ushort*)(ws + (18 << 20));          // 4 MB
  float*  o   = (float*)(ws + (22 << 20));           // 8 MB
  float*  gate= (float*)(ws + (30 << 20));           // 16 KB

  hipLaunchKernelGGL(conv_x_kernel, dim3(Y_SIZE / 1024), dim3(256), 0, stream, x, xb);
  hipLaunchKernelGGL(conv_wt_kernel, dim3(8, 8, 4), dim3(256), 0, stream,
                     wq, wk, wv, wo, wqt, wkt, wvt, wot);
  hipLaunchKernelGGL(proj_qkv_kernel, dim3(64, 8, 3), dim3(256), 0, stream,
                     xb, wqt, bq, wkt, bk, wvt, bv, qb, kb, vt);
  hipLaunchKernelGGL(gate_kernel, dim3(512), dim3(256), 0, stream,
                     x, g1w, g1b, g2w, g2b, gate);
  hipLaunchKernelGGL(attn_kernel, dim3(32, 16), dim3(256), 0, stream,
                     qb, kb, vt, attn, ctx);
  hipLaunchKernelGGL(proj_o_kernel, dim3(64, 8), dim3(256), 0, stream,
                     ctx, wot, bo, o);
  hipLaunchKernelGGL(blend_ln_kernel, dim3(4096), dim3(256), 0, stream,
                     o, x, gate, lng, lnb, y);
}